// Round 10
// baseline (2639.918 us; speedup 1.0000x reference)
//
#include <hip/hip_runtime.h>
#include <math.h>

typedef unsigned long long u64;
typedef unsigned int u32;

#define MAXS 16
#define NB 4
#define IH 720
#define IW 1280
#define OFFC 5120.0f   // 4.0 * max(h,w)
#define KG 2048

// ---------------- shared host/device structs ----------------
struct SInfo {
  int oh, ow, hp, wp, h2, w2, hc, wc, n, k;
  float scf;
  int img_off, pool_off, c2_off, nk_off, cand_base;
  int g1x, g1y, g2x, g2y, g3x, g3y;
};
struct PAll {
  SInfo s[MAXS];
  int blkRZ[MAXS+1], blkC1[MAXS+1], blkC2[MAXS+1], blkH[MAXS+1];
  int ns;
};
struct RedEnt { int in_buf, blk_start, nblk, in_off, out_off, n; };
struct RedArgs { RedEnt e[MAXS]; int ne, outk; };
struct FinEnt { int in_buf, in_off, n, k, hc, wc, cand_base, nk_off; float scf; };
struct FinArgs { FinEnt e[MAXS]; };
struct SMArgs { int base[MAXS], kk[MAXS], blk[MAXS+1], ns; };
struct SSArgs { int base[MAXS], kk[MAXS]; };

// ---------------- key helpers: total order matching lax.top_k ----------------
__device__ __forceinline__ u64 makekey(float v, unsigned idx) {
  unsigned b = __float_as_uint(v);
  unsigned u = (b & 0x80000000u) ? ~b : (b | 0x80000000u);
  return ((u64)u << 32) | (unsigned)(~idx);
}
__device__ __forceinline__ float keyval(u64 c) {
  unsigned u = (unsigned)(c >> 32);
  unsigned b = (u & 0x80000000u) ? (u ^ 0x80000000u) : ~u;
  return __uint_as_float(b);
}

// ---------------- 1. fused area resize + normalize (one dispatch, all scales) ----------
// Phase 1 vectorized to float4; per-column sum chains unchanged -> bit-exact.
__global__ __launch_bounds__(256) void k_resize_f(const float* __restrict__ img,
                                                  float* __restrict__ out, PAll P) {
  __shared__ float4 sh4[IW/4];
  float* sh = (float*)sh4;
  int blk = blockIdx.x, si = 0;
  while (si + 1 < P.ns && blk >= P.blkRZ[si+1]) ++si;
  SInfo S = P.s[si];
  int row = blk - P.blkRZ[si];          // in [0, NB*3*oh)
  int y = row % S.oh; int bc = row / S.oh;
  int hs = (y*IH)/S.oh, he = ((y+1)*IH + S.oh - 1)/S.oh;
  float rh = 1.0f/(float)(he-hs);
  const float4* bp4 = (const float4*)(img + (size_t)bc*IH*IW);
  for (int x4 = threadIdx.x; x4 < IW/4; x4 += 256) {
    float4 cs = make_float4(0.f, 0.f, 0.f, 0.f);
    for (int yy = hs; yy < he; ++yy) {
      float4 v = bp4[(size_t)yy*(IW/4) + x4];
      cs.x += v.x*rh; cs.y += v.y*rh; cs.z += v.z*rh; cs.w += v.w*rh;
    }
    sh4[x4] = cs;
  }
  __syncthreads();
  for (int xo = threadIdx.x; xo < S.ow; xo += 256) {
    int ws_ = (xo*IW)/S.ow, we_ = ((xo+1)*IW + S.ow - 1)/S.ow;
    float rw = 1.0f/(float)(we_-ws_);
    float acc = 0.f;
    for (int xx = ws_; xx < we_; ++xx) acc += sh[xx] * rw;
    out[S.img_off + (size_t)row*S.ow + xo] = (acc - 127.5f) * 0.0078125f;
  }
}

// ---------------- 2. conv1(3x3,10ch)+PReLU+ceil-maxpool2, LDS-tiled ----------------
__global__ __launch_bounds__(256) void k_conv1pool_t(const float* __restrict__ rsz,
    const float* __restrict__ w1, const float* __restrict__ b1, const float* __restrict__ a1,
    float* __restrict__ pool, PAll P) {
  __shared__ float sh[3*10*130];
  int blk = blockIdx.x, si = 0;
  while (si + 1 < P.ns && blk >= P.blkC1[si+1]) ++si;
  SInfo S = P.s[si];
  int rem = blk - P.blkC1[si];
  int tiles = S.g1x * S.g1y;
  int b = rem / tiles; int r2 = rem % tiles;
  int ty0 = (r2 / S.g1x) * 4, tx0 = (r2 % S.g1x) * 64;
  int tx = threadIdx.x & 63, ty = threadIdx.x >> 6;

  for (int idx = threadIdx.x; idx < 3*10*130; idx += 256) {
    int cc = idx % 130; int t = idx / 130;
    int rr = t % 10; int c = t / 10;
    int gr = 2*ty0 + rr, gc = 2*tx0 + cc;
    float v = 0.f;
    if (gr < S.oh && gc < S.ow)
      v = rsz[S.img_off + ((b*3 + c)*S.oh + gr)*S.ow + gc];
    sh[(c*10 + rr)*130 + cc] = v;
  }
  __syncthreads();

  int x = tx0 + tx, y = ty0 + ty;
  if (x >= S.wp || y >= S.hp) return;
  int H1 = S.oh - 2, W1 = S.ow - 2;
  float m[10];
  #pragma unroll
  for (int o = 0; o < 10; ++o) m[o] = -INFINITY;
  for (int dy = 0; dy < 2; ++dy) {
    int ry = 2*y + dy; if (ry >= H1) continue;
    int lr = 2*ty + dy;
    for (int dx = 0; dx < 2; ++dx) {
      int rx = 2*x + dx; if (rx >= W1) continue;
      int lc = 2*tx + dx;
      float v[10];
      #pragma unroll
      for (int o = 0; o < 10; ++o) v[o] = 0.f;
      for (int c = 0; c < 3; ++c)
        #pragma unroll
        for (int ky = 0; ky < 3; ++ky)
          #pragma unroll
          for (int kx = 0; kx < 3; ++kx) {
            float s = sh[(c*10 + lr + ky)*130 + lc + kx];
            #pragma unroll
            for (int o = 0; o < 10; ++o)
              v[o] += s * w1[((o*3 + c)*3 + ky)*3 + kx];
          }
      #pragma unroll
      for (int o = 0; o < 10; ++o) {
        float vv = v[o] + b1[o];
        vv = vv > 0.f ? vv : a1[o]*vv;
        m[o] = fmaxf(m[o], vv);
      }
    }
  }
  #pragma unroll
  for (int o = 0; o < 10; ++o)
    pool[S.pool_off + ((b*10 + o)*S.hp + y)*S.wp + x] = m[o];
}

// ---------------- 3. conv2(3x3,10->16)+PReLU, LDS-tiled ----------------
__global__ __launch_bounds__(256) void k_conv2_t(const float* __restrict__ pool,
    const float* __restrict__ w2, const float* __restrict__ b2w, const float* __restrict__ a2,
    float* __restrict__ c2o, PAll P) {
  __shared__ float sh[10*6*66];
  int blk = blockIdx.x, si = 0;
  while (si + 1 < P.ns && blk >= P.blkC2[si+1]) ++si;
  SInfo S = P.s[si];
  int rem = blk - P.blkC2[si];
  int tiles = S.g2x * S.g2y;
  int b = rem / tiles; int r2 = rem % tiles;
  int ty0 = (r2 / S.g2x) * 4, tx0 = (r2 % S.g2x) * 64;
  int tx = threadIdx.x & 63, ty = threadIdx.x >> 6;

  for (int idx = threadIdx.x; idx < 10*6*66; idx += 256) {
    int cc = idx % 66; int t = idx / 66;
    int rr = t % 6; int c = t / 6;
    int gr = ty0 + rr, gc = tx0 + cc;
    float v = 0.f;
    if (gr < S.hp && gc < S.wp)
      v = pool[S.pool_off + ((b*10 + c)*S.hp + gr)*S.wp + gc];
    sh[(c*6 + rr)*66 + cc] = v;
  }
  __syncthreads();

  int x = tx0 + tx, y = ty0 + ty;
  if (x >= S.w2 || y >= S.h2) return;
  float acc[16];
  #pragma unroll
  for (int o = 0; o < 16; ++o) acc[o] = 0.f;
  for (int c = 0; c < 10; ++c)
    #pragma unroll
    for (int ky = 0; ky < 3; ++ky)
      #pragma unroll
      for (int kx = 0; kx < 3; ++kx) {
        float s = sh[(c*6 + ty + ky)*66 + tx + kx];
        #pragma unroll
        for (int o = 0; o < 16; ++o)
          acc[o] += s * w2[((o*10 + c)*3 + ky)*3 + kx];
      }
  #pragma unroll
  for (int o = 0; o < 16; ++o) {
    float v = acc[o] + b2w[o];
    v = v > 0.f ? v : a2[o]*v;
    c2o[S.c2_off + ((b*16 + o)*S.h2 + y)*S.w2 + x] = v;
  }
}

// ---------------- 4. conv3+heads, WAVE-LEVEL oc-split ----------
// Ledger: R2/R6 acc[32] LB(256): VGPR 100, 330us. R4 2-row: VGPR 160, 900us.
// R7 LB(256,6): spill, 2870us. R8 thread-level oc-split: VGPR 208, 1700us.
// Now: oc halves on DIFFERENT WAVES (waves 0-1: oc0-15, waves 2-3: oc16-31;
// `half` forced scalar via readfirstlane so w3 stays s_load). Per-thread state
// acc[16]+v[16], no sequential half loop to interleave. Head sums bit-exact:
// half0 writes its oc0-15 left-assoc partial to LDS; half1 CONTINUES the same
// chain (l0 = p0; l0 += t16; ...; += b41) -- identical association to ref.
__global__ __launch_bounds__(256) void k_conv3heads_t(const float* __restrict__ c2,
    const float* __restrict__ w3, const float* __restrict__ b3, const float* __restrict__ a3,
    const float* __restrict__ w41, const float* __restrict__ b41,
    const float* __restrict__ w42, const float* __restrict__ b42,
    u64* __restrict__ keys, float4* __restrict__ reg4, PAll P) {
  __shared__ float sh[16*4*66];   // input tile 16ch x 4 rows x 66 cols = 16.5 KB
  __shared__ float ph[6*128];     // head-sum handoff (3 KB)
  int blk = blockIdx.x, si = 0;
  while (si + 1 < P.ns && blk >= P.blkH[si+1]) ++si;
  SInfo S = P.s[si];
  int rem = blk - P.blkH[si];
  int tiles = S.g3x * S.g3y;
  int b = rem / tiles; int r2 = rem % tiles;
  int ty0 = (r2 / S.g3x) * 2, tx0 = (r2 % S.g3x) * 64;
  int tx = threadIdx.x & 63;
  int trow = (threadIdx.x >> 6) & 1;                               // output row 0..1
  int half = __builtin_amdgcn_readfirstlane(threadIdx.x >> 7);     // wave-uniform oc half
  int pos = threadIdx.x & 127;
  int ocb = half * 16;

  for (int idx = threadIdx.x; idx < 16*4*66; idx += 256) {
    int cc = idx % 66; int t = idx / 66;
    int rr = t % 4; int c = t / 4;
    int gr = ty0 + rr, gc = tx0 + cc;
    float v = 0.f;
    if (gr < S.h2 && gc < S.w2)
      v = c2[S.c2_off + ((b*16 + c)*S.h2 + gr)*S.w2 + gc];
    sh[(c*4 + rr)*66 + cc] = v;
  }
  __syncthreads();

  int x = tx0 + tx, y = ty0 + trow;
  bool ok = (x < S.wc) && (y < S.hc);
  float acc[16];
  if (ok) {
    #pragma unroll
    for (int o = 0; o < 16; ++o) acc[o] = 0.f;
    #pragma unroll
    for (int ky = 0; ky < 3; ++ky)
      #pragma unroll
      for (int kx = 0; kx < 3; ++kx) {
        float v[16];
        #pragma unroll
        for (int ic = 0; ic < 16; ++ic) v[ic] = sh[(ic*4 + trow + ky)*66 + tx + kx];
        #pragma unroll
        for (int o = 0; o < 16; ++o) {
          float tt = 0.f;
          #pragma unroll
          for (int ic = 0; ic < 16; ++ic)
            tt += v[ic] * w3[(((ocb + o)*16 + ic)*3 + ky)*3 + kx];
          acc[o] += tt;
        }
      }
  }
  if (half == 0) {
    if (ok) {
      float l0 = 0.f, l1 = 0.f, r0 = 0.f, r1 = 0.f, r2v = 0.f, r3 = 0.f;
      #pragma unroll
      for (int o = 0; o < 16; ++o) {
        float vv = acc[o] + b3[o];
        vv = vv > 0.f ? vv : a3[o]*vv;
        l0 += vv * w41[o];      l1 += vv * w41[32 + o];
        r0 += vv * w42[o];      r1 += vv * w42[32 + o];
        r2v += vv * w42[64 + o]; r3 += vv * w42[96 + o];
      }
      ph[pos] = l0; ph[128 + pos] = l1; ph[256 + pos] = r0;
      ph[384 + pos] = r1; ph[512 + pos] = r2v; ph[640 + pos] = r3;
    }
  }
  __syncthreads();
  if (half == 1 && ok) {
    float l0 = ph[pos], l1 = ph[128 + pos], r0 = ph[256 + pos],
          r1 = ph[384 + pos], r2v = ph[512 + pos], r3 = ph[640 + pos];
    #pragma unroll
    for (int o = 0; o < 16; ++o) {
      int oc = 16 + o;
      float vv = acc[o] + b3[oc];
      vv = vv > 0.f ? vv : a3[oc]*vv;
      l0 += vv * w41[oc];      l1 += vv * w41[32 + oc];
      r0 += vv * w42[oc];      r1 += vv * w42[32 + oc];
      r2v += vv * w42[64 + oc]; r3 += vv * w42[96 + oc];
    }
    l0 += b41[0]; l1 += b41[1];
    r0 += b42[0]; r1 += b42[1]; r2v += b42[2]; r3 += b42[3];
    float mx = fmaxf(l0, l1);
    float e0 = expf(l0 - mx), e1 = expf(l1 - mx);
    float score = e1 / (e0 + e1);
    float kv = (score >= 0.6f) ? score : -INFINITY;
    int local = (b*S.hc + y)*S.wc + x;
    keys[S.nk_off + local] = makekey(kv, (unsigned)local);
    reg4[S.nk_off + local] = make_float4(r0, r1, r2v, r3);
  }
}

// ---------------- bitonic sort (4096, descending) in LDS ----------------
// Pair-indexed: 8 all-lanes-active iterations (was 16 with half masked off).
// Identical compare-exchange network -> identical result.
__device__ inline void bitonic4096_desc(u64* sh) {
  for (int kk = 2; kk <= 4096; kk <<= 1)
    for (int j = kk >> 1; j > 0; j >>= 1) {
      __syncthreads();
      for (int p = threadIdx.x; p < 2048; p += 256) {
        int low = p & (j - 1);
        int i = ((p ^ low) << 1) | low;   // bit log2(j) of i is 0
        int ixj = i | j;
        u64 a = sh[i], b = sh[ixj];
        if (((i & kk) == 0) ? (a < b) : (a > b)) { sh[i] = b; sh[ixj] = a; }
      }
    }
  __syncthreads();
}

// ---------------- 5. hierarchical top-k reduce ----------------
__global__ __launch_bounds__(256) void k_topk_reduce(const u64* __restrict__ b0,
    const u64* __restrict__ b1, const u64* __restrict__ b2, const u64* __restrict__ b3,
    u64* __restrict__ outb, RedArgs ra) {
  __shared__ u64 sh[4096];
  int blk = blockIdx.x, ei = 0;
  while (ei + 1 < ra.ne && blk >= ra.e[ei].blk_start + ra.e[ei].nblk) ++ei;
  RedEnt e = ra.e[ei];
  int chunk = blk - e.blk_start;
  const u64* in = (e.in_buf == 0 ? b0 : e.in_buf == 1 ? b1 : e.in_buf == 2 ? b2 : b3)
                  + e.in_off + (size_t)chunk*4096;
  int m = e.n - chunk*4096; if (m > 4096) m = 4096;
  for (int i = threadIdx.x; i < 4096; i += 256) sh[i] = (i < m) ? in[i] : 0ULL;
  bitonic4096_desc(sh);
  u64* o = outb + e.out_off + (size_t)chunk * ra.outk;
  for (int i = threadIdx.x; i < ra.outk; i += 256) o[i] = sh[i];
}

// ---------------- 6. final per-scale sort + gather + NMS-SoA prep (fused) ----------
__global__ __launch_bounds__(256) void k_final_gather(const u64* __restrict__ b0,
    const u64* __restrict__ b1, const u64* __restrict__ b2,
    const float4* __restrict__ reg4, float* __restrict__ cb9, int* __restrict__ cinds,
    float* __restrict__ cx1, float* __restrict__ cy1, float* __restrict__ cx2,
    float* __restrict__ cy2, float* __restrict__ car, float* __restrict__ csc,
    FinArgs fa) {
  __shared__ u64 sh[4096];
  FinEnt f = fa.e[blockIdx.x];
  const u64* in = (f.in_buf == 0 ? b0 : f.in_buf == 1 ? b1 : b2) + f.in_off;
  for (int i = threadIdx.x; i < 4096; i += 256) sh[i] = (i < f.n) ? in[i] : 0ULL;
  bitonic4096_desc(sh);
  for (int i = threadIdx.x; i < f.k; i += 256) {
    u64 c = sh[i];
    float val = keyval(c);
    unsigned idx = ~(unsigned)c;
    int x = (int)(idx % (unsigned)f.wc); unsigned t2 = idx / (unsigned)f.wc;
    int y = (int)(t2 % (unsigned)f.hc); int b = (int)(t2 / (unsigned)f.hc);
    float cx = (float)x, cy = (float)y;
    float x1 = floorf((2.0f*cx + 1.0f)/f.scf);
    float y1 = floorf((2.0f*cy + 1.0f)/f.scf);
    float x2 = floorf((2.0f*cx + 12.0f)/f.scf);
    float y2 = floorf((2.0f*cy + 12.0f)/f.scf);
    float4 rg = reg4[f.nk_off + idx];
    int g = f.cand_base + i;
    float* p = cb9 + (size_t)g*9;
    p[0]=x1; p[1]=y1; p[2]=x2; p[3]=y2; p[4]=val;
    p[5]=rg.x; p[6]=rg.y; p[7]=rg.z; p[8]=rg.w;
    cinds[g] = b;
    float off = OFFC * (float)b;
    float a = x1 + off, bb = y1 + off, cc2 = x2 + off, d = y2 + off;
    cx1[g]=a; cy1[g]=bb; cx2[g]=cc2; cy2[g]=d;
    car[g] = (cc2 - a + 1.0f) * (d - bb + 1.0f);
    csc[g] = val;
  }
}

// ---------------- 7b. per-scale suppression-mask build, TRANSPOSED layout ----------
__global__ __launch_bounds__(256) void k_smask(const float* __restrict__ cx1,
    const float* __restrict__ cy1, const float* __restrict__ cx2,
    const float* __restrict__ cy2, const float* __restrict__ car,
    u32* __restrict__ mask, SMArgs ma) {
  __shared__ float sb[5][1024];
  int blk = blockIdx.x, si = 0;
  while (si + 1 < ma.ns && blk >= ma.blk[si+1]) ++si;
  int base = ma.base[si], k = ma.kk[si];
  for (int idx = threadIdx.x; idx < k; idx += 256) {
    sb[0][idx] = cx1[base+idx]; sb[1][idx] = cy1[base+idx];
    sb[2][idx] = cx2[base+idx]; sb[3][idx] = cy2[base+idx];
    sb[4][idx] = car[base+idx];
  }
  __syncthreads();
  int rem = blk - ma.blk[si];
  int rg = rem >> 2, cg = rem & 3;
  int i = rg*32 + (threadIdx.x & 31);
  int c = cg*8 + (threadIdx.x >> 5);
  if (i >= k) return;
  float xi1 = sb[0][i], yi1 = sb[1][i], xi2 = sb[2][i], yi2 = sb[3][i], ai = sb[4][i];
  u32 bits = 0;
  #pragma unroll 8
  for (int b = 0; b < 32; ++b) {
    int j = b*32 + c;
    if (j > i && j < k) {
      float iw = fminf(xi2, sb[2][j]) - fmaxf(xi1, sb[0][j]) + 1.0f; iw = fmaxf(iw, 0.0f);
      float ih = fminf(yi2, sb[3][j]) - fmaxf(yi1, sb[1][j]) + 1.0f; ih = fmaxf(ih, 0.0f);
      float inter = iw*ih;
      if (inter / (ai + sb[4][j] - inter) > 0.5f) bits |= 1u << b;
    }
  }
  mask[(size_t)base*32 + (size_t)c*k + i] = bits;
}

// ---------------- 7c. per-scale greedy scan, register-pipelined (1 wave/scale) ------
#define SPROC(ROW, IDX)                                   \
  if ((IDX) < k) {                                        \
    int ci = (IDX) & 31, bi = (IDX) >> 5;                 \
    u32 supo = (u32)__shfl((int)sup, ci);                 \
    if (!((supo >> bi) & 1u)) {                           \
      if (lane == ci) kept |= 1u << bi;                   \
      sup |= (ROW);                                       \
    }                                                     \
  }

__global__ __launch_bounds__(64) void k_sscan(const u32* __restrict__ mask,
    const float* __restrict__ csc, u64* __restrict__ candk, SSArgs sa) {
  int s = blockIdx.x, base = sa.base[s], k = sa.kk[s];
  int lane = threadIdx.x;
  u32 validm = 0;
  if (lane < 32) {
    for (int b = 0; b < 32; ++b) {
      int j = b*32 + lane;
      if (j < k && csc[base+j] != -INFINITY) validm |= 1u << b;
    }
  }
  u32 sup = ~validm, kept = 0;
  const u32* mt = mask + (size_t)base*32 + (size_t)(lane & 31)*k;
  const uint4 z4 = make_uint4(0u,0u,0u,0u);
  #define SLD4(I) ((lane < 32 && (I) < k) ? *(const uint4*)(mt + (I)) : z4)
  uint4 q0 = SLD4(0), q1 = SLD4(4), q2 = SLD4(8), q3 = SLD4(12);
  for (int i = 0; i < k; i += 16) {
    SPROC(q0.x, i+0) SPROC(q0.y, i+1) SPROC(q0.z, i+2) SPROC(q0.w, i+3)
    q0 = SLD4(i+16);
    SPROC(q1.x, i+4) SPROC(q1.y, i+5) SPROC(q1.z, i+6) SPROC(q1.w, i+7)
    q1 = SLD4(i+20);
    SPROC(q2.x, i+8) SPROC(q2.y, i+9) SPROC(q2.z, i+10) SPROC(q2.w, i+11)
    q2 = SLD4(i+24);
    SPROC(q3.x, i+12) SPROC(q3.y, i+13) SPROC(q3.z, i+14) SPROC(q3.w, i+15)
    q3 = SLD4(i+28);
  }
  #undef SLD4
  if (lane < 32) {
    for (int b = 0; b < 32; ++b) {
      int j = b*32 + lane;
      if (j < k) {
        float v = ((kept >> b) & 1u) ? csc[base+j] : -INFINITY;
        candk[base + j] = makekey(v, (unsigned)(base + j));
      }
    }
  }
}

// ---------------- 8. global final sort (4096 -> top 2048) + SoA prep (fused) --------
__global__ __launch_bounds__(256) void k_gfinal(const u64* __restrict__ in,
    const float* __restrict__ cb9, const int* __restrict__ cinds,
    u64* __restrict__ gs, float* __restrict__ gx1, float* __restrict__ gy1,
    float* __restrict__ gx2, float* __restrict__ gy2, float* __restrict__ gar,
    float* __restrict__ gsc) {
  __shared__ u64 sh[4096];
  for (int i = threadIdx.x; i < 4096; i += 256) sh[i] = in[i];
  bitonic4096_desc(sh);
  for (int i = threadIdx.x; i < KG; i += 256) {
    u64 c = sh[i];
    gs[i] = c;
    unsigned g = ~(unsigned)c;
    const float* p = cb9 + (size_t)g*9;
    float off = OFFC * (float)cinds[g];
    float a = p[0] + off, b = p[1] + off, cc = p[2] + off, d = p[3] + off;
    gx1[i]=a; gy1[i]=b; gx2[i]=cc; gy2[i]=d;
    gar[i] = (cc - a + 1.0f) * (d - b + 1.0f);
    gsc[i] = keyval(c);
  }
}

// ---------------- 9b. global mask build, TRANSPOSED: maskT[c*KG + i] ----------
__global__ __launch_bounds__(256) void k_gmask(const float* __restrict__ gx1,
    const float* __restrict__ gy1, const float* __restrict__ gx2,
    const float* __restrict__ gy2, const float* __restrict__ gar,
    u32* __restrict__ gmask) {
  __shared__ float sb[5][KG];
  for (int idx = threadIdx.x; idx < KG; idx += 256) {
    sb[0][idx] = gx1[idx]; sb[1][idx] = gy1[idx];
    sb[2][idx] = gx2[idx]; sb[3][idx] = gy2[idx]; sb[4][idx] = gar[idx];
  }
  __syncthreads();
  int rg = blockIdx.x >> 4, cg = blockIdx.x & 15;
  int i = rg*64 + (threadIdx.x & 63);
  int c = cg*4 + (threadIdx.x >> 6);
  float xi1 = sb[0][i], yi1 = sb[1][i], xi2 = sb[2][i], yi2 = sb[3][i], ai = sb[4][i];
  u32 bits = 0;
  #pragma unroll 8
  for (int b = 0; b < 32; ++b) {
    int j = b*64 + c;
    if (j > i) {
      float iw = fminf(xi2, sb[2][j]) - fmaxf(xi1, sb[0][j]) + 1.0f; iw = fmaxf(iw, 0.0f);
      float ih = fminf(yi2, sb[3][j]) - fmaxf(yi1, sb[1][j]) + 1.0f; ih = fmaxf(ih, 0.0f);
      float inter = iw*ih;
      if (inter / (ai + sb[4][j] - inter) > 0.7f) bits |= 1u << b;
    }
  }
  gmask[(size_t)c*KG + i] = bits;
}

// ---------------- 9c. global greedy scan, register-pipelined (1 wave) ----------
#define GPROC(ROW, IDX)                                   \
  {                                                       \
    int ci = (IDX) & 63, bi = (IDX) >> 6;                 \
    u32 supo = (u32)__shfl((int)sup, ci);                 \
    if (!((supo >> bi) & 1u)) {                           \
      if (lane == ci) kept |= 1u << bi;                   \
      sup |= (ROW);                                       \
    }                                                     \
  }

__global__ __launch_bounds__(64) void k_gscan(const u32* __restrict__ gmask,
    const float* __restrict__ gsc, int* __restrict__ gkeep) {
  int lane = threadIdx.x;
  u32 validm = 0;
  for (int b = 0; b < 32; ++b) {
    int j = b*64 + lane;
    if (gsc[j] != -INFINITY) validm |= 1u << b;
  }
  u32 sup = ~validm, kept = 0;
  const u32* mt = gmask + (size_t)lane*KG;
  #define GLD4(I) (*(const uint4*)(mt + (I)))
  uint4 q0 = GLD4(0), q1 = GLD4(4), q2 = GLD4(8), q3 = GLD4(12);
  for (int i = 0; i < KG; i += 16) {
    GPROC(q0.x, i+0) GPROC(q0.y, i+1) GPROC(q0.z, i+2) GPROC(q0.w, i+3)
    if (i+16 < KG) q0 = GLD4(i+16);
    GPROC(q1.x, i+4) GPROC(q1.y, i+5) GPROC(q1.z, i+6) GPROC(q1.w, i+7)
    if (i+20 < KG) q1 = GLD4(i+20);
    GPROC(q2.x, i+8) GPROC(q2.y, i+9) GPROC(q2.z, i+10) GPROC(q2.w, i+11)
    if (i+24 < KG) q2 = GLD4(i+24);
    GPROC(q3.x, i+12) GPROC(q3.y, i+13) GPROC(q3.z, i+14) GPROC(q3.w, i+15)
    if (i+28 < KG) q3 = GLD4(i+28);
  }
  #undef GLD4
  for (int b = 0; b < 32; ++b) gkeep[b*64 + lane] = (int)((kept >> b) & 1u);
}

// ---------------- 10. refinement + output ----------------
__global__ __launch_bounds__(256) void k_finalize(const u64* __restrict__ gs,
    const int* __restrict__ gkeep, const float* __restrict__ cb9, const int* __restrict__ cinds,
    float* __restrict__ out) {
  int r = blockIdx.x*256 + threadIdx.x;
  if (r >= KG) return;
  u64 c = gs[r];
  unsigned g = ~(unsigned)c;
  float val = keyval(c);
  const float* p = cb9 + (size_t)g*9;
  int ind = cinds[g];
  bool valid = (val != -INFINITY) && (gkeep[r] != 0);
  float b0=p[0], b1v=p[1], b2v=p[2], b3=p[3], sc=p[4], r5=p[5], r6=p[6], r7=p[7], r8=p[8];
  float regw = b2v - b0, regh = b3 - b1v;
  float qq1 = b0 + r5*regw, qq2 = b1v + r6*regh, qq3 = b2v + r7*regw, qq4 = b3 + r8*regh;
  float bw = qq3 - qq1, bh = qq4 - qq2;
  float l = fmaxf(bw, bh);
  float x1n = qq1 + bw*0.5f - l*0.5f;
  float y1n = qq2 + bh*0.5f - l*0.5f;
  float o0 = x1n, o1 = y1n, o2 = x1n + l, o3 = y1n + l, o4 = sc;
  if (!valid) { o0=o1=o2=o3=o4=0.f; }
  out[r*5+0]=o0; out[r*5+1]=o1; out[r*5+2]=o2; out[r*5+3]=o3; out[r*5+4]=o4;
  out[5*KG + r] = valid ? 1.0f : 0.0f;
  out[6*KG + r] = (float)ind;
}

// ---------------- host ----------------
extern "C" void kernel_launch(void* const* d_in, const int* in_sizes, int n_in,
                              void* d_out, int out_size, void* d_ws, size_t ws_size,
                              hipStream_t stream) {
  (void)in_sizes; (void)n_in; (void)out_size;
  const float* imgs = (const float*)d_in[0];
  const float* c1w  = (const float*)d_in[1];
  const float* c1b  = (const float*)d_in[2];
  const float* a1   = (const float*)d_in[3];
  const float* c2w  = (const float*)d_in[4];
  const float* c2b  = (const float*)d_in[5];
  const float* a2   = (const float*)d_in[6];
  const float* c3w  = (const float*)d_in[7];
  const float* c3b  = (const float*)d_in[8];
  const float* a3   = (const float*)d_in[9];
  const float* c41w = (const float*)d_in[10];
  const float* c41b = (const float*)d_in[11];
  const float* c42w = (const float*)d_in[12];
  const float* c42b = (const float*)d_in[13];
  float* out = (float*)d_out;

  int ns = 0; double scl[MAXS];
  { double mm = 12.0/20.0; double minl = 720.0*mm; double ss = mm;
    while (minl >= 12.0 && ns < MAXS) { scl[ns++] = ss; ss *= 0.709; minl *= 0.709; } }

  PAll P{}; P.ns = ns;
  int tot_img=0, tot_pool=0, tot_c2=0, tot_n=0, tot_k=0;
  P.blkRZ[0]=P.blkC1[0]=P.blkC2[0]=P.blkH[0]=0;
  for (int i = 0; i < ns; ++i) {
    SInfo& S = P.s[i];
    S.oh = (int)(720.0*scl[i] + 1.0); S.ow = (int)(1280.0*scl[i] + 1.0);
    int h1 = S.oh-2, w1 = S.ow-2;
    S.hp = (h1+1)/2; S.wp = (w1+1)/2;
    S.h2 = S.hp-2; S.w2 = S.wp-2;
    S.hc = S.hp-4; S.wc = S.wp-4;
    S.n = NB*S.hc*S.wc;
    S.k = S.n < 1024 ? S.n : 1024;   // always a multiple of 4 (n = 4*hc*wc)
    S.scf = (float)scl[i];
    S.img_off = tot_img;   tot_img  += NB*3*S.oh*S.ow;
    S.pool_off = tot_pool; tot_pool += NB*10*S.hp*S.wp;
    S.c2_off = tot_c2;     tot_c2   += NB*16*S.h2*S.w2;
    S.nk_off = tot_n;      tot_n    += S.n;
    S.cand_base = tot_k;   tot_k    += S.k;
    S.g1x = (S.wp + 63)/64; S.g1y = (S.hp + 3)/4;
    S.g2x = (S.w2 + 63)/64; S.g2y = (S.h2 + 3)/4;
    S.g3x = (S.wc + 63)/64; S.g3y = (S.hc + 1)/2;   // conv3 tile is now 64x2
    P.blkRZ[i+1] = P.blkRZ[i] + NB*3*S.oh;
    P.blkC1[i+1] = P.blkC1[i] + S.g1x*S.g1y*NB;
    P.blkC2[i+1] = P.blkC2[i] + S.g2x*S.g2y*NB;
    P.blkH[i+1]  = P.blkH[i]  + S.g3x*S.g3y*NB;
  }

  int regA[MAXS] = {0}, regB[MAXS] = {0};
  long offA = 0, offB = 0;
  for (int i = 0; i < ns; ++i) {
    if (P.s[i].n > 4096) {
      int nb = (P.s[i].n + 4095)/4096;
      regA[i] = (int)offA; offA += (long)nb*1024;
      int n1 = nb*1024;
      if (n1 > 4096) { int nb1 = (n1 + 4095)/4096; regB[i] = (int)offB; offB += (long)nb1*1024; }
    }
  }
  long redAe = offA > 6144 ? offA : 6144;
  long redBe = offB > 4096 ? offB : 4096;

  char* wsb = (char*)d_ws; size_t wo = 0;
  auto take = [&](size_t bytes)->size_t { size_t r = wo; wo += (bytes + 255) & ~(size_t)255; return r; };
  float*  rsz    = (float*) (wsb + take((size_t)tot_img*4));
  float*  poolb  = (float*) (wsb + take((size_t)tot_pool*4));
  float*  c2buf  = (float*) (wsb + take((size_t)tot_c2*4));
  float4* reg4   = (float4*)(wsb + take((size_t)tot_n*16));
  u64*    keys   = (u64*)   (wsb + take((size_t)tot_n*8));
  u64*    redA   = (u64*)   (wsb + take((size_t)redAe*8));
  u64*    redB   = (u64*)   (wsb + take((size_t)redBe*8));
  float*  cb9    = (float*) (wsb + take((size_t)tot_k*9*4));
  int*    cinds  = (int*)   (wsb + take((size_t)tot_k*4));
  u64*    candk  = (u64*)   (wsb + take((size_t)tot_k*8));
  u64*    gsort  = (u64*)   (wsb + take((size_t)KG*8));
  int*    gkeep  = (int*)   (wsb + take((size_t)KG*4));
  float*  cx1 = (float*)(wsb + take((size_t)tot_k*4));
  float*  cy1 = (float*)(wsb + take((size_t)tot_k*4));
  float*  cx2 = (float*)(wsb + take((size_t)tot_k*4));
  float*  cy2 = (float*)(wsb + take((size_t)tot_k*4));
  float*  car = (float*)(wsb + take((size_t)tot_k*4));
  float*  csc = (float*)(wsb + take((size_t)tot_k*4));
  u32*    smask = (u32*)(wsb + take((size_t)tot_k*32*4));
  float*  gx1 = (float*)(wsb + take((size_t)KG*4));
  float*  gy1 = (float*)(wsb + take((size_t)KG*4));
  float*  gx2 = (float*)(wsb + take((size_t)KG*4));
  float*  gy2 = (float*)(wsb + take((size_t)KG*4));
  float*  gar = (float*)(wsb + take((size_t)KG*4));
  float*  gsc = (float*)(wsb + take((size_t)KG*4));
  u32*    gmaskb = (u32*)(wsb + take((size_t)KG*64*4));
  if (wo > ws_size) return;  // insufficient workspace

  k_resize_f    <<<P.blkRZ[ns], 256, 0, stream>>>(imgs, rsz, P);
  k_conv1pool_t <<<P.blkC1[ns], 256, 0, stream>>>(rsz, c1w, c1b, a1, poolb, P);
  k_conv2_t     <<<P.blkC2[ns], 256, 0, stream>>>(poolb, c2w, c2b, a2, c2buf, P);
  k_conv3heads_t<<<P.blkH[ns],  256, 0, stream>>>(c2buf, c3w, c3b, a3, c41w, c41b, c42w, c42b,
                                                  keys, reg4, P);

  // per-scale hierarchical top-k
  struct Cur { int buf, off, n; } cur[MAXS];
  for (int i = 0; i < ns; ++i) { cur[i].buf = 0; cur[i].off = P.s[i].nk_off; cur[i].n = P.s[i].n; }
  for (int stage = 0; ; ++stage) {
    RedArgs ra{}; ra.ne = 0; ra.outk = 1024; int tb = 0;
    int ob = (stage & 1) ? 2 : 1;
    for (int i = 0; i < ns; ++i) if (cur[i].n > 4096) {
      int nb = (cur[i].n + 4095)/4096;
      RedEnt& e = ra.e[ra.ne++];
      e.in_buf = cur[i].buf; e.in_off = cur[i].off; e.n = cur[i].n;
      e.blk_start = tb; e.nblk = nb;
      e.out_off = (ob == 1) ? regA[i] : regB[i];
      tb += nb;
      cur[i].buf = ob; cur[i].off = e.out_off; cur[i].n = nb*1024;
    }
    if (!ra.ne) break;
    k_topk_reduce<<<tb, 256, 0, stream>>>(keys, redA, redB, candk,
                                          (ob == 1) ? redA : redB, ra);
  }

  FinArgs fa{};
  for (int i = 0; i < ns; ++i) {
    FinEnt& f = fa.e[i];
    f.in_buf = cur[i].buf; f.in_off = cur[i].off; f.n = cur[i].n;
    f.k = P.s[i].k; f.hc = P.s[i].hc; f.wc = P.s[i].wc;
    f.cand_base = P.s[i].cand_base; f.nk_off = P.s[i].nk_off; f.scf = P.s[i].scf;
  }
  k_final_gather<<<ns, 256, 0, stream>>>(keys, redA, redB, reg4, cb9, cinds,
                                         cx1, cy1, cx2, cy2, car, csc, fa);

  // per-scale NMS: mask (transposed) -> register-pipelined scan
  SMArgs ma{}; ma.ns = ns; ma.blk[0] = 0;
  SSArgs sa{};
  for (int i = 0; i < ns; ++i) {
    ma.base[i] = P.s[i].cand_base; ma.kk[i] = P.s[i].k;
    ma.blk[i+1] = ma.blk[i] + ((P.s[i].k + 31)/32) * 4;
    sa.base[i] = P.s[i].cand_base; sa.kk[i] = P.s[i].k;
  }
  k_smask<<<ma.blk[ns], 256, 0, stream>>>(cx1, cy1, cx2, cy2, car, smask, ma);
  k_sscan<<<ns, 64, 0, stream>>>(smask, csc, candk, sa);

  // global top-2048
  {
    int nb1 = (tot_k + 4095)/4096;
    RedArgs ra{}; ra.ne = 1; ra.outk = KG;
    ra.e[0].in_buf = 3; ra.e[0].in_off = 0; ra.e[0].n = tot_k;
    ra.e[0].blk_start = 0; ra.e[0].nblk = nb1; ra.e[0].out_off = 0;
    k_topk_reduce<<<nb1, 256, 0, stream>>>(keys, redA, redB, candk, redA, ra);
    int n2 = nb1*KG;
    int nb2 = (n2 + 4095)/4096;
    RedArgs rb{}; rb.ne = 1; rb.outk = KG;
    rb.e[0].in_buf = 1; rb.e[0].in_off = 0; rb.e[0].n = n2;
    rb.e[0].blk_start = 0; rb.e[0].nblk = nb2; rb.e[0].out_off = 0;
    k_topk_reduce<<<nb2, 256, 0, stream>>>(keys, redA, redB, candk, redB, rb);
  }
  k_gfinal<<<1, 256, 0, stream>>>(redB, cb9, cinds, gsort, gx1, gy1, gx2, gy2, gar, gsc);

  // global NMS: transposed mask -> register-pipelined scan
  k_gmask<<<512, 256, 0, stream>>>(gx1, gy1, gx2, gy2, gar, gmaskb);
  k_gscan<<<1, 64, 0, stream>>>(gmaskb, gsc, gkeep);

  k_finalize<<<(KG + 255)/256, 256, 0, stream>>>(gsort, gkeep, cb9, cinds, out);
}

// Round 11
// 1748.593 us; speedup vs baseline: 1.5097x; 1.5097x over previous
//
#include <hip/hip_runtime.h>
#include <math.h>

typedef unsigned long long u64;
typedef unsigned int u32;

#define MAXS 16
#define NB 4
#define IH 720
#define IW 1280
#define OFFC 5120.0f   // 4.0 * max(h,w)
#define KG 2048

// ---------------- shared host/device structs ----------------
struct SInfo {
  int oh, ow, hp, wp, h2, w2, hc, wc, n, k;
  float scf;
  int img_off, pool_off, c2_off, nk_off, cand_base;
  int g1x, g1y, g2x, g2y, g3x, g3y;
};
struct PAll {
  SInfo s[MAXS];
  int blkRZ[MAXS+1], blkC1[MAXS+1], blkC2[MAXS+1], blkH[MAXS+1];
  int ns;
};
struct RedEnt { int in_buf, blk_start, nblk, in_off, out_off, n; };
struct RedArgs { RedEnt e[MAXS]; int ne, outk; };
struct FinEnt { int in_buf, in_off, n, k, hc, wc, cand_base, nk_off; float scf; };
struct FinArgs { FinEnt e[MAXS]; };
struct SMArgs { int base[MAXS], kk[MAXS], blk[MAXS+1], ns; };
struct SSArgs { int base[MAXS], kk[MAXS]; };

// ---------------- key helpers: total order matching lax.top_k ----------------
__device__ __forceinline__ u64 makekey(float v, unsigned idx) {
  unsigned b = __float_as_uint(v);
  unsigned u = (b & 0x80000000u) ? ~b : (b | 0x80000000u);
  return ((u64)u << 32) | (unsigned)(~idx);
}
__device__ __forceinline__ float keyval(u64 c) {
  unsigned u = (unsigned)(c >> 32);
  unsigned b = (u & 0x80000000u) ? (u ^ 0x80000000u) : ~u;
  return __uint_as_float(b);
}

// ---------------- 1. fused area resize + normalize (one dispatch, all scales) ----------
// Phase 1 vectorized to float4; per-column sum chains unchanged -> bit-exact.
__global__ __launch_bounds__(256) void k_resize_f(const float* __restrict__ img,
                                                  float* __restrict__ out, PAll P) {
  __shared__ float4 sh4[IW/4];
  float* sh = (float*)sh4;
  int blk = blockIdx.x, si = 0;
  while (si + 1 < P.ns && blk >= P.blkRZ[si+1]) ++si;
  SInfo S = P.s[si];
  int row = blk - P.blkRZ[si];          // in [0, NB*3*oh)
  int y = row % S.oh; int bc = row / S.oh;
  int hs = (y*IH)/S.oh, he = ((y+1)*IH + S.oh - 1)/S.oh;
  float rh = 1.0f/(float)(he-hs);
  const float4* bp4 = (const float4*)(img + (size_t)bc*IH*IW);
  for (int x4 = threadIdx.x; x4 < IW/4; x4 += 256) {
    float4 cs = make_float4(0.f, 0.f, 0.f, 0.f);
    for (int yy = hs; yy < he; ++yy) {
      float4 v = bp4[(size_t)yy*(IW/4) + x4];
      cs.x += v.x*rh; cs.y += v.y*rh; cs.z += v.z*rh; cs.w += v.w*rh;
    }
    sh4[x4] = cs;
  }
  __syncthreads();
  for (int xo = threadIdx.x; xo < S.ow; xo += 256) {
    int ws_ = (xo*IW)/S.ow, we_ = ((xo+1)*IW + S.ow - 1)/S.ow;
    float rw = 1.0f/(float)(we_-ws_);
    float acc = 0.f;
    for (int xx = ws_; xx < we_; ++xx) acc += sh[xx] * rw;
    out[S.img_off + (size_t)row*S.ow + xo] = (acc - 127.5f) * 0.0078125f;
  }
}

// ---------------- 2. conv1(3x3,10ch)+PReLU+ceil-maxpool2, LDS-tiled ----------------
__global__ __launch_bounds__(256) void k_conv1pool_t(const float* __restrict__ rsz,
    const float* __restrict__ w1, const float* __restrict__ b1, const float* __restrict__ a1,
    float* __restrict__ pool, PAll P) {
  __shared__ float sh[3*10*130];
  int blk = blockIdx.x, si = 0;
  while (si + 1 < P.ns && blk >= P.blkC1[si+1]) ++si;
  SInfo S = P.s[si];
  int rem = blk - P.blkC1[si];
  int tiles = S.g1x * S.g1y;
  int b = rem / tiles; int r2 = rem % tiles;
  int ty0 = (r2 / S.g1x) * 4, tx0 = (r2 % S.g1x) * 64;
  int tx = threadIdx.x & 63, ty = threadIdx.x >> 6;

  for (int idx = threadIdx.x; idx < 3*10*130; idx += 256) {
    int cc = idx % 130; int t = idx / 130;
    int rr = t % 10; int c = t / 10;
    int gr = 2*ty0 + rr, gc = 2*tx0 + cc;
    float v = 0.f;
    if (gr < S.oh && gc < S.ow)
      v = rsz[S.img_off + ((b*3 + c)*S.oh + gr)*S.ow + gc];
    sh[(c*10 + rr)*130 + cc] = v;
  }
  __syncthreads();

  int x = tx0 + tx, y = ty0 + ty;
  if (x >= S.wp || y >= S.hp) return;
  int H1 = S.oh - 2, W1 = S.ow - 2;
  float m[10];
  #pragma unroll
  for (int o = 0; o < 10; ++o) m[o] = -INFINITY;
  for (int dy = 0; dy < 2; ++dy) {
    int ry = 2*y + dy; if (ry >= H1) continue;
    int lr = 2*ty + dy;
    for (int dx = 0; dx < 2; ++dx) {
      int rx = 2*x + dx; if (rx >= W1) continue;
      int lc = 2*tx + dx;
      float v[10];
      #pragma unroll
      for (int o = 0; o < 10; ++o) v[o] = 0.f;
      for (int c = 0; c < 3; ++c)
        #pragma unroll
        for (int ky = 0; ky < 3; ++ky)
          #pragma unroll
          for (int kx = 0; kx < 3; ++kx) {
            float s = sh[(c*10 + lr + ky)*130 + lc + kx];
            #pragma unroll
            for (int o = 0; o < 10; ++o)
              v[o] += s * w1[((o*3 + c)*3 + ky)*3 + kx];
          }
      #pragma unroll
      for (int o = 0; o < 10; ++o) {
        float vv = v[o] + b1[o];
        vv = vv > 0.f ? vv : a1[o]*vv;
        m[o] = fmaxf(m[o], vv);
      }
    }
  }
  #pragma unroll
  for (int o = 0; o < 10; ++o)
    pool[S.pool_off + ((b*10 + o)*S.hp + y)*S.wp + x] = m[o];
}

// ---------------- 3. conv2(3x3,10->16)+PReLU, LDS-tiled ----------------
__global__ __launch_bounds__(256) void k_conv2_t(const float* __restrict__ pool,
    const float* __restrict__ w2, const float* __restrict__ b2w, const float* __restrict__ a2,
    float* __restrict__ c2o, PAll P) {
  __shared__ float sh[10*6*66];
  int blk = blockIdx.x, si = 0;
  while (si + 1 < P.ns && blk >= P.blkC2[si+1]) ++si;
  SInfo S = P.s[si];
  int rem = blk - P.blkC2[si];
  int tiles = S.g2x * S.g2y;
  int b = rem / tiles; int r2 = rem % tiles;
  int ty0 = (r2 / S.g2x) * 4, tx0 = (r2 % S.g2x) * 64;
  int tx = threadIdx.x & 63, ty = threadIdx.x >> 6;

  for (int idx = threadIdx.x; idx < 10*6*66; idx += 256) {
    int cc = idx % 66; int t = idx / 66;
    int rr = t % 6; int c = t / 6;
    int gr = ty0 + rr, gc = tx0 + cc;
    float v = 0.f;
    if (gr < S.hp && gc < S.wp)
      v = pool[S.pool_off + ((b*10 + c)*S.hp + gr)*S.wp + gc];
    sh[(c*6 + rr)*66 + cc] = v;
  }
  __syncthreads();

  int x = tx0 + tx, y = ty0 + ty;
  if (x >= S.w2 || y >= S.h2) return;
  float acc[16];
  #pragma unroll
  for (int o = 0; o < 16; ++o) acc[o] = 0.f;
  for (int c = 0; c < 10; ++c)
    #pragma unroll
    for (int ky = 0; ky < 3; ++ky)
      #pragma unroll
      for (int kx = 0; kx < 3; ++kx) {
        float s = sh[(c*6 + ty + ky)*66 + tx + kx];
        #pragma unroll
        for (int o = 0; o < 16; ++o)
          acc[o] += s * w2[((o*10 + c)*3 + ky)*3 + kx];
      }
  #pragma unroll
  for (int o = 0; o < 16; ++o) {
    float v = acc[o] + b2w[o];
    v = v > 0.f ? v : a2[o]*v;
    c2o[S.c2_off + ((b*16 + o)*S.h2 + y)*S.w2 + x] = v;
  }
}

// ---------------- 4. conv3(3x3,16->32)+PReLU + heads + softmax (R6 EXACT, FROZEN) ----
// Register-allocation knife-edge. FINAL ledger — 5 variants measured:
//   R2/R6 acc[32]+v[16], LB(256):  VGPR 100, occ 22%, ~336 us  <- OPTIMUM. FROZEN.
//   R4 2 rows/thread:              VGPR 160, occ 11%,  900 us
//   R7 oc-split + LB(256,6):       VGPR  40 + scratch SPILL, 2870 us
//   R8 thread-level oc-split:      VGPR 208 (halves interleaved), 1700 us
//   R10 wave-level oc-split:       VGPR 80, occ 34%, VALU 5x (dup LDS), 1230 us
// DO NOT TOUCH THIS KERNEL.
__global__ __launch_bounds__(256) void k_conv3heads_t(const float* __restrict__ c2,
    const float* __restrict__ w3, const float* __restrict__ b3, const float* __restrict__ a3,
    const float* __restrict__ w41, const float* __restrict__ b41,
    const float* __restrict__ w42, const float* __restrict__ b42,
    u64* __restrict__ keys, float4* __restrict__ reg4, PAll P) {
  __shared__ float sh[16*6*66];    // 25.3 KB
  int blk = blockIdx.x, si = 0;
  while (si + 1 < P.ns && blk >= P.blkH[si+1]) ++si;
  SInfo S = P.s[si];
  int rem = blk - P.blkH[si];
  int tiles = S.g3x * S.g3y;
  int b = rem / tiles; int r2 = rem % tiles;
  int ty0 = (r2 / S.g3x) * 4, tx0 = (r2 % S.g3x) * 64;
  int tx = threadIdx.x & 63, ty = threadIdx.x >> 6;

  for (int idx = threadIdx.x; idx < 16*6*66; idx += 256) {
    int cc = idx % 66; int t = idx / 66;
    int rr = t % 6; int c = t / 6;
    int gr = ty0 + rr, gc = tx0 + cc;
    float v = 0.f;
    if (gr < S.h2 && gc < S.w2)
      v = c2[S.c2_off + ((b*16 + c)*S.h2 + gr)*S.w2 + gc];
    sh[(c*6 + rr)*66 + cc] = v;
  }
  __syncthreads();

  int x = tx0 + tx, y = ty0 + ty;
  if (x >= S.wc || y >= S.hc) return;
  float acc[32];
  #pragma unroll
  for (int oc = 0; oc < 32; ++oc) acc[oc] = 0.f;
  #pragma unroll
  for (int ky = 0; ky < 3; ++ky)
    #pragma unroll
    for (int kx = 0; kx < 3; ++kx) {
      float v[16];
      #pragma unroll
      for (int ic = 0; ic < 16; ++ic) v[ic] = sh[(ic*6 + ty + ky)*66 + tx + kx];
      #pragma unroll
      for (int oc = 0; oc < 32; ++oc) {
        float tt = 0.f;
        #pragma unroll
        for (int ic = 0; ic < 16; ++ic)
          tt += v[ic] * w3[((oc*16 + ic)*3 + ky)*3 + kx];
        acc[oc] += tt;
      }
    }
  float l0 = 0.f, l1 = 0.f, r0 = 0.f, r1 = 0.f, r2v = 0.f, r3 = 0.f;
  #pragma unroll
  for (int oc = 0; oc < 32; ++oc) {
    float vv = acc[oc] + b3[oc];
    vv = vv > 0.f ? vv : a3[oc]*vv;
    l0 += vv * w41[oc];      l1 += vv * w41[32 + oc];
    r0 += vv * w42[oc];      r1 += vv * w42[32 + oc];
    r2v += vv * w42[64 + oc]; r3 += vv * w42[96 + oc];
  }
  l0 += b41[0]; l1 += b41[1];
  r0 += b42[0]; r1 += b42[1]; r2v += b42[2]; r3 += b42[3];
  float mx = fmaxf(l0, l1);
  float e0 = expf(l0 - mx), e1 = expf(l1 - mx);
  float score = e1 / (e0 + e1);
  float kv = (score >= 0.6f) ? score : -INFINITY;
  int local = (b*S.hc + y)*S.wc + x;
  keys[S.nk_off + local] = makekey(kv, (unsigned)local);
  reg4[S.nk_off + local] = make_float4(r0, r1, r2v, r3);
}

// ---------------- bitonic sort (4096, descending) in LDS ----------------
// Pair-indexed: 8 all-lanes-active iterations (was 16 half-masked).
// Identical compare-exchange network. [R10: ~550 us total saving across sorts]
__device__ inline void bitonic4096_desc(u64* sh) {
  for (int kk = 2; kk <= 4096; kk <<= 1)
    for (int j = kk >> 1; j > 0; j >>= 1) {
      __syncthreads();
      for (int p = threadIdx.x; p < 2048; p += 256) {
        int low = p & (j - 1);
        int i = ((p ^ low) << 1) | low;   // bit log2(j) of i is 0
        int ixj = i | j;
        u64 a = sh[i], b = sh[ixj];
        if (((i & kk) == 0) ? (a < b) : (a > b)) { sh[i] = b; sh[ixj] = a; }
      }
    }
  __syncthreads();
}

// ---------------- 5. hierarchical top-k reduce ----------------
__global__ __launch_bounds__(256) void k_topk_reduce(const u64* __restrict__ b0,
    const u64* __restrict__ b1, const u64* __restrict__ b2, const u64* __restrict__ b3,
    u64* __restrict__ outb, RedArgs ra) {
  __shared__ u64 sh[4096];
  int blk = blockIdx.x, ei = 0;
  while (ei + 1 < ra.ne && blk >= ra.e[ei].blk_start + ra.e[ei].nblk) ++ei;
  RedEnt e = ra.e[ei];
  int chunk = blk - e.blk_start;
  const u64* in = (e.in_buf == 0 ? b0 : e.in_buf == 1 ? b1 : e.in_buf == 2 ? b2 : b3)
                  + e.in_off + (size_t)chunk*4096;
  int m = e.n - chunk*4096; if (m > 4096) m = 4096;
  for (int i = threadIdx.x; i < 4096; i += 256) sh[i] = (i < m) ? in[i] : 0ULL;
  bitonic4096_desc(sh);
  u64* o = outb + e.out_off + (size_t)chunk * ra.outk;
  for (int i = threadIdx.x; i < ra.outk; i += 256) o[i] = sh[i];
}

// ---------------- 6. final per-scale sort + gather + NMS-SoA prep (fused) ----------
__global__ __launch_bounds__(256) void k_final_gather(const u64* __restrict__ b0,
    const u64* __restrict__ b1, const u64* __restrict__ b2,
    const float4* __restrict__ reg4, float* __restrict__ cb9, int* __restrict__ cinds,
    float* __restrict__ cx1, float* __restrict__ cy1, float* __restrict__ cx2,
    float* __restrict__ cy2, float* __restrict__ car, float* __restrict__ csc,
    FinArgs fa) {
  __shared__ u64 sh[4096];
  FinEnt f = fa.e[blockIdx.x];
  const u64* in = (f.in_buf == 0 ? b0 : f.in_buf == 1 ? b1 : b2) + f.in_off;
  for (int i = threadIdx.x; i < 4096; i += 256) sh[i] = (i < f.n) ? in[i] : 0ULL;
  bitonic4096_desc(sh);
  for (int i = threadIdx.x; i < f.k; i += 256) {
    u64 c = sh[i];
    float val = keyval(c);
    unsigned idx = ~(unsigned)c;
    int x = (int)(idx % (unsigned)f.wc); unsigned t2 = idx / (unsigned)f.wc;
    int y = (int)(t2 % (unsigned)f.hc); int b = (int)(t2 / (unsigned)f.hc);
    float cx = (float)x, cy = (float)y;
    float x1 = floorf((2.0f*cx + 1.0f)/f.scf);
    float y1 = floorf((2.0f*cy + 1.0f)/f.scf);
    float x2 = floorf((2.0f*cx + 12.0f)/f.scf);
    float y2 = floorf((2.0f*cy + 12.0f)/f.scf);
    float4 rg = reg4[f.nk_off + idx];
    int g = f.cand_base + i;
    float* p = cb9 + (size_t)g*9;
    p[0]=x1; p[1]=y1; p[2]=x2; p[3]=y2; p[4]=val;
    p[5]=rg.x; p[6]=rg.y; p[7]=rg.z; p[8]=rg.w;
    cinds[g] = b;
    float off = OFFC * (float)b;
    float a = x1 + off, bb = y1 + off, cc2 = x2 + off, d = y2 + off;
    cx1[g]=a; cy1[g]=bb; cx2[g]=cc2; cy2[g]=d;
    car[g] = (cc2 - a + 1.0f) * (d - bb + 1.0f);
    csc[g] = val;
  }
}

// ---------------- 7b. per-scale suppression-mask build, TRANSPOSED layout ----------
__global__ __launch_bounds__(256) void k_smask(const float* __restrict__ cx1,
    const float* __restrict__ cy1, const float* __restrict__ cx2,
    const float* __restrict__ cy2, const float* __restrict__ car,
    u32* __restrict__ mask, SMArgs ma) {
  __shared__ float sb[5][1024];
  int blk = blockIdx.x, si = 0;
  while (si + 1 < ma.ns && blk >= ma.blk[si+1]) ++si;
  int base = ma.base[si], k = ma.kk[si];
  for (int idx = threadIdx.x; idx < k; idx += 256) {
    sb[0][idx] = cx1[base+idx]; sb[1][idx] = cy1[base+idx];
    sb[2][idx] = cx2[base+idx]; sb[3][idx] = cy2[base+idx];
    sb[4][idx] = car[base+idx];
  }
  __syncthreads();
  int rem = blk - ma.blk[si];
  int rg = rem >> 2, cg = rem & 3;
  int i = rg*32 + (threadIdx.x & 31);
  int c = cg*8 + (threadIdx.x >> 5);
  if (i >= k) return;
  float xi1 = sb[0][i], yi1 = sb[1][i], xi2 = sb[2][i], yi2 = sb[3][i], ai = sb[4][i];
  u32 bits = 0;
  #pragma unroll 8
  for (int b = 0; b < 32; ++b) {
    int j = b*32 + c;
    if (j > i && j < k) {
      float iw = fminf(xi2, sb[2][j]) - fmaxf(xi1, sb[0][j]) + 1.0f; iw = fmaxf(iw, 0.0f);
      float ih = fminf(yi2, sb[3][j]) - fmaxf(yi1, sb[1][j]) + 1.0f; ih = fmaxf(ih, 0.0f);
      float inter = iw*ih;
      if (inter / (ai + sb[4][j] - inter) > 0.5f) bits |= 1u << b;
    }
  }
  mask[(size_t)base*32 + (size_t)c*k + i] = bits;
}

// ---------------- 7c. per-scale greedy scan, register-pipelined (1 wave/scale) ------
#define SPROC(ROW, IDX)                                   \
  if ((IDX) < k) {                                        \
    int ci = (IDX) & 31, bi = (IDX) >> 5;                 \
    u32 supo = (u32)__shfl((int)sup, ci);                 \
    if (!((supo >> bi) & 1u)) {                           \
      if (lane == ci) kept |= 1u << bi;                   \
      sup |= (ROW);                                       \
    }                                                     \
  }

__global__ __launch_bounds__(64) void k_sscan(const u32* __restrict__ mask,
    const float* __restrict__ csc, u64* __restrict__ candk, SSArgs sa) {
  int s = blockIdx.x, base = sa.base[s], k = sa.kk[s];
  int lane = threadIdx.x;
  u32 validm = 0;
  if (lane < 32) {
    for (int b = 0; b < 32; ++b) {
      int j = b*32 + lane;
      if (j < k && csc[base+j] != -INFINITY) validm |= 1u << b;
    }
  }
  u32 sup = ~validm, kept = 0;
  const u32* mt = mask + (size_t)base*32 + (size_t)(lane & 31)*k;
  const uint4 z4 = make_uint4(0u,0u,0u,0u);
  #define SLD4(I) ((lane < 32 && (I) < k) ? *(const uint4*)(mt + (I)) : z4)
  uint4 q0 = SLD4(0), q1 = SLD4(4), q2 = SLD4(8), q3 = SLD4(12);
  for (int i = 0; i < k; i += 16) {
    SPROC(q0.x, i+0) SPROC(q0.y, i+1) SPROC(q0.z, i+2) SPROC(q0.w, i+3)
    q0 = SLD4(i+16);
    SPROC(q1.x, i+4) SPROC(q1.y, i+5) SPROC(q1.z, i+6) SPROC(q1.w, i+7)
    q1 = SLD4(i+20);
    SPROC(q2.x, i+8) SPROC(q2.y, i+9) SPROC(q2.z, i+10) SPROC(q2.w, i+11)
    q2 = SLD4(i+24);
    SPROC(q3.x, i+12) SPROC(q3.y, i+13) SPROC(q3.z, i+14) SPROC(q3.w, i+15)
    q3 = SLD4(i+28);
  }
  #undef SLD4
  if (lane < 32) {
    for (int b = 0; b < 32; ++b) {
      int j = b*32 + lane;
      if (j < k) {
        float v = ((kept >> b) & 1u) ? csc[base+j] : -INFINITY;
        candk[base + j] = makekey(v, (unsigned)(base + j));
      }
    }
  }
}

// ---------------- 8. global final sort (4096 -> top 2048) + SoA prep (fused) --------
__global__ __launch_bounds__(256) void k_gfinal(const u64* __restrict__ in,
    const float* __restrict__ cb9, const int* __restrict__ cinds,
    u64* __restrict__ gs, float* __restrict__ gx1, float* __restrict__ gy1,
    float* __restrict__ gx2, float* __restrict__ gy2, float* __restrict__ gar,
    float* __restrict__ gsc) {
  __shared__ u64 sh[4096];
  for (int i = threadIdx.x; i < 4096; i += 256) sh[i] = in[i];
  bitonic4096_desc(sh);
  for (int i = threadIdx.x; i < KG; i += 256) {
    u64 c = sh[i];
    gs[i] = c;
    unsigned g = ~(unsigned)c;
    const float* p = cb9 + (size_t)g*9;
    float off = OFFC * (float)cinds[g];
    float a = p[0] + off, b = p[1] + off, cc = p[2] + off, d = p[3] + off;
    gx1[i]=a; gy1[i]=b; gx2[i]=cc; gy2[i]=d;
    gar[i] = (cc - a + 1.0f) * (d - b + 1.0f);
    gsc[i] = keyval(c);
  }
}

// ---------------- 9b. global mask build, TRANSPOSED: maskT[c*KG + i] ----------
__global__ __launch_bounds__(256) void k_gmask(const float* __restrict__ gx1,
    const float* __restrict__ gy1, const float* __restrict__ gx2,
    const float* __restrict__ gy2, const float* __restrict__ gar,
    u32* __restrict__ gmask) {
  __shared__ float sb[5][KG];
  for (int idx = threadIdx.x; idx < KG; idx += 256) {
    sb[0][idx] = gx1[idx]; sb[1][idx] = gy1[idx];
    sb[2][idx] = gx2[idx]; sb[3][idx] = gy2[idx]; sb[4][idx] = gar[idx];
  }
  __syncthreads();
  int rg = blockIdx.x >> 4, cg = blockIdx.x & 15;
  int i = rg*64 + (threadIdx.x & 63);
  int c = cg*4 + (threadIdx.x >> 6);
  float xi1 = sb[0][i], yi1 = sb[1][i], xi2 = sb[2][i], yi2 = sb[3][i], ai = sb[4][i];
  u32 bits = 0;
  #pragma unroll 8
  for (int b = 0; b < 32; ++b) {
    int j = b*64 + c;
    if (j > i) {
      float iw = fminf(xi2, sb[2][j]) - fmaxf(xi1, sb[0][j]) + 1.0f; iw = fmaxf(iw, 0.0f);
      float ih = fminf(yi2, sb[3][j]) - fmaxf(yi1, sb[1][j]) + 1.0f; ih = fmaxf(ih, 0.0f);
      float inter = iw*ih;
      if (inter / (ai + sb[4][j] - inter) > 0.7f) bits |= 1u << b;
    }
  }
  gmask[(size_t)c*KG + i] = bits;
}

// ---------------- 9c. global greedy scan, register-pipelined (1 wave) ----------
#define GPROC(ROW, IDX)                                   \
  {                                                       \
    int ci = (IDX) & 63, bi = (IDX) >> 6;                 \
    u32 supo = (u32)__shfl((int)sup, ci);                 \
    if (!((supo >> bi) & 1u)) {                           \
      if (lane == ci) kept |= 1u << bi;                   \
      sup |= (ROW);                                       \
    }                                                     \
  }

__global__ __launch_bounds__(64) void k_gscan(const u32* __restrict__ gmask,
    const float* __restrict__ gsc, int* __restrict__ gkeep) {
  int lane = threadIdx.x;
  u32 validm = 0;
  for (int b = 0; b < 32; ++b) {
    int j = b*64 + lane;
    if (gsc[j] != -INFINITY) validm |= 1u << b;
  }
  u32 sup = ~validm, kept = 0;
  const u32* mt = gmask + (size_t)lane*KG;
  #define GLD4(I) (*(const uint4*)(mt + (I)))
  uint4 q0 = GLD4(0), q1 = GLD4(4), q2 = GLD4(8), q3 = GLD4(12);
  for (int i = 0; i < KG; i += 16) {
    GPROC(q0.x, i+0) GPROC(q0.y, i+1) GPROC(q0.z, i+2) GPROC(q0.w, i+3)
    if (i+16 < KG) q0 = GLD4(i+16);
    GPROC(q1.x, i+4) GPROC(q1.y, i+5) GPROC(q1.z, i+6) GPROC(q1.w, i+7)
    if (i+20 < KG) q1 = GLD4(i+20);
    GPROC(q2.x, i+8) GPROC(q2.y, i+9) GPROC(q2.z, i+10) GPROC(q2.w, i+11)
    if (i+24 < KG) q2 = GLD4(i+24);
    GPROC(q3.x, i+12) GPROC(q3.y, i+13) GPROC(q3.z, i+14) GPROC(q3.w, i+15)
    if (i+28 < KG) q3 = GLD4(i+28);
  }
  #undef GLD4
  for (int b = 0; b < 32; ++b) gkeep[b*64 + lane] = (int)((kept >> b) & 1u);
}

// ---------------- 10. refinement + output ----------------
__global__ __launch_bounds__(256) void k_finalize(const u64* __restrict__ gs,
    const int* __restrict__ gkeep, const float* __restrict__ cb9, const int* __restrict__ cinds,
    float* __restrict__ out) {
  int r = blockIdx.x*256 + threadIdx.x;
  if (r >= KG) return;
  u64 c = gs[r];
  unsigned g = ~(unsigned)c;
  float val = keyval(c);
  const float* p = cb9 + (size_t)g*9;
  int ind = cinds[g];
  bool valid = (val != -INFINITY) && (gkeep[r] != 0);
  float b0=p[0], b1v=p[1], b2v=p[2], b3=p[3], sc=p[4], r5=p[5], r6=p[6], r7=p[7], r8=p[8];
  float regw = b2v - b0, regh = b3 - b1v;
  float qq1 = b0 + r5*regw, qq2 = b1v + r6*regh, qq3 = b2v + r7*regw, qq4 = b3 + r8*regh;
  float bw = qq3 - qq1, bh = qq4 - qq2;
  float l = fmaxf(bw, bh);
  float x1n = qq1 + bw*0.5f - l*0.5f;
  float y1n = qq2 + bh*0.5f - l*0.5f;
  float o0 = x1n, o1 = y1n, o2 = x1n + l, o3 = y1n + l, o4 = sc;
  if (!valid) { o0=o1=o2=o3=o4=0.f; }
  out[r*5+0]=o0; out[r*5+1]=o1; out[r*5+2]=o2; out[r*5+3]=o3; out[r*5+4]=o4;
  out[5*KG + r] = valid ? 1.0f : 0.0f;
  out[6*KG + r] = (float)ind;
}

// ---------------- host ----------------
extern "C" void kernel_launch(void* const* d_in, const int* in_sizes, int n_in,
                              void* d_out, int out_size, void* d_ws, size_t ws_size,
                              hipStream_t stream) {
  (void)in_sizes; (void)n_in; (void)out_size;
  const float* imgs = (const float*)d_in[0];
  const float* c1w  = (const float*)d_in[1];
  const float* c1b  = (const float*)d_in[2];
  const float* a1   = (const float*)d_in[3];
  const float* c2w  = (const float*)d_in[4];
  const float* c2b  = (const float*)d_in[5];
  const float* a2   = (const float*)d_in[6];
  const float* c3w  = (const float*)d_in[7];
  const float* c3b  = (const float*)d_in[8];
  const float* a3   = (const float*)d_in[9];
  const float* c41w = (const float*)d_in[10];
  const float* c41b = (const float*)d_in[11];
  const float* c42w = (const float*)d_in[12];
  const float* c42b = (const float*)d_in[13];
  float* out = (float*)d_out;

  int ns = 0; double scl[MAXS];
  { double mm = 12.0/20.0; double minl = 720.0*mm; double ss = mm;
    while (minl >= 12.0 && ns < MAXS) { scl[ns++] = ss; ss *= 0.709; minl *= 0.709; } }

  PAll P{}; P.ns = ns;
  int tot_img=0, tot_pool=0, tot_c2=0, tot_n=0, tot_k=0;
  P.blkRZ[0]=P.blkC1[0]=P.blkC2[0]=P.blkH[0]=0;
  for (int i = 0; i < ns; ++i) {
    SInfo& S = P.s[i];
    S.oh = (int)(720.0*scl[i] + 1.0); S.ow = (int)(1280.0*scl[i] + 1.0);
    int h1 = S.oh-2, w1 = S.ow-2;
    S.hp = (h1+1)/2; S.wp = (w1+1)/2;
    S.h2 = S.hp-2; S.w2 = S.wp-2;
    S.hc = S.hp-4; S.wc = S.wp-4;
    S.n = NB*S.hc*S.wc;
    S.k = S.n < 1024 ? S.n : 1024;   // always a multiple of 4 (n = 4*hc*wc)
    S.scf = (float)scl[i];
    S.img_off = tot_img;   tot_img  += NB*3*S.oh*S.ow;
    S.pool_off = tot_pool; tot_pool += NB*10*S.hp*S.wp;
    S.c2_off = tot_c2;     tot_c2   += NB*16*S.h2*S.w2;
    S.nk_off = tot_n;      tot_n    += S.n;
    S.cand_base = tot_k;   tot_k    += S.k;
    S.g1x = (S.wp + 63)/64; S.g1y = (S.hp + 3)/4;
    S.g2x = (S.w2 + 63)/64; S.g2y = (S.h2 + 3)/4;
    S.g3x = (S.wc + 63)/64; S.g3y = (S.hc + 3)/4;   // R6 conv3 tile: 64x4
    P.blkRZ[i+1] = P.blkRZ[i] + NB*3*S.oh;
    P.blkC1[i+1] = P.blkC1[i] + S.g1x*S.g1y*NB;
    P.blkC2[i+1] = P.blkC2[i] + S.g2x*S.g2y*NB;
    P.blkH[i+1]  = P.blkH[i]  + S.g3x*S.g3y*NB;
  }

  int regA[MAXS] = {0}, regB[MAXS] = {0};
  long offA = 0, offB = 0;
  for (int i = 0; i < ns; ++i) {
    if (P.s[i].n > 4096) {
      int nb = (P.s[i].n + 4095)/4096;
      regA[i] = (int)offA; offA += (long)nb*1024;
      int n1 = nb*1024;
      if (n1 > 4096) { int nb1 = (n1 + 4095)/4096; regB[i] = (int)offB; offB += (long)nb1*1024; }
    }
  }
  long redAe = offA > 6144 ? offA : 6144;
  long redBe = offB > 4096 ? offB : 4096;

  char* wsb = (char*)d_ws; size_t wo = 0;
  auto take = [&](size_t bytes)->size_t { size_t r = wo; wo += (bytes + 255) & ~(size_t)255; return r; };
  float*  rsz    = (float*) (wsb + take((size_t)tot_img*4));
  float*  poolb  = (float*) (wsb + take((size_t)tot_pool*4));
  float*  c2buf  = (float*) (wsb + take((size_t)tot_c2*4));
  float4* reg4   = (float4*)(wsb + take((size_t)tot_n*16));
  u64*    keys   = (u64*)   (wsb + take((size_t)tot_n*8));
  u64*    redA   = (u64*)   (wsb + take((size_t)redAe*8));
  u64*    redB   = (u64*)   (wsb + take((size_t)redBe*8));
  float*  cb9    = (float*) (wsb + take((size_t)tot_k*9*4));
  int*    cinds  = (int*)   (wsb + take((size_t)tot_k*4));
  u64*    candk  = (u64*)   (wsb + take((size_t)tot_k*8));
  u64*    gsort  = (u64*)   (wsb + take((size_t)KG*8));
  int*    gkeep  = (int*)   (wsb + take((size_t)KG*4));
  float*  cx1 = (float*)(wsb + take((size_t)tot_k*4));
  float*  cy1 = (float*)(wsb + take((size_t)tot_k*4));
  float*  cx2 = (float*)(wsb + take((size_t)tot_k*4));
  float*  cy2 = (float*)(wsb + take((size_t)tot_k*4));
  float*  car = (float*)(wsb + take((size_t)tot_k*4));
  float*  csc = (float*)(wsb + take((size_t)tot_k*4));
  u32*    smask = (u32*)(wsb + take((size_t)tot_k*32*4));
  float*  gx1 = (float*)(wsb + take((size_t)KG*4));
  float*  gy1 = (float*)(wsb + take((size_t)KG*4));
  float*  gx2 = (float*)(wsb + take((size_t)KG*4));
  float*  gy2 = (float*)(wsb + take((size_t)KG*4));
  float*  gar = (float*)(wsb + take((size_t)KG*4));
  float*  gsc = (float*)(wsb + take((size_t)KG*4));
  u32*    gmaskb = (u32*)(wsb + take((size_t)KG*64*4));
  if (wo > ws_size) return;  // insufficient workspace

  k_resize_f    <<<P.blkRZ[ns], 256, 0, stream>>>(imgs, rsz, P);
  k_conv1pool_t <<<P.blkC1[ns], 256, 0, stream>>>(rsz, c1w, c1b, a1, poolb, P);
  k_conv2_t     <<<P.blkC2[ns], 256, 0, stream>>>(poolb, c2w, c2b, a2, c2buf, P);
  k_conv3heads_t<<<P.blkH[ns],  256, 0, stream>>>(c2buf, c3w, c3b, a3, c41w, c41b, c42w, c42b,
                                                  keys, reg4, P);

  // per-scale hierarchical top-k
  struct Cur { int buf, off, n; } cur[MAXS];
  for (int i = 0; i < ns; ++i) { cur[i].buf = 0; cur[i].off = P.s[i].nk_off; cur[i].n = P.s[i].n; }
  for (int stage = 0; ; ++stage) {
    RedArgs ra{}; ra.ne = 0; ra.outk = 1024; int tb = 0;
    int ob = (stage & 1) ? 2 : 1;
    for (int i = 0; i < ns; ++i) if (cur[i].n > 4096) {
      int nb = (cur[i].n + 4095)/4096;
      RedEnt& e = ra.e[ra.ne++];
      e.in_buf = cur[i].buf; e.in_off = cur[i].off; e.n = cur[i].n;
      e.blk_start = tb; e.nblk = nb;
      e.out_off = (ob == 1) ? regA[i] : regB[i];
      tb += nb;
      cur[i].buf = ob; cur[i].off = e.out_off; cur[i].n = nb*1024;
    }
    if (!ra.ne) break;
    k_topk_reduce<<<tb, 256, 0, stream>>>(keys, redA, redB, candk,
                                          (ob == 1) ? redA : redB, ra);
  }

  FinArgs fa{};
  for (int i = 0; i < ns; ++i) {
    FinEnt& f = fa.e[i];
    f.in_buf = cur[i].buf; f.in_off = cur[i].off; f.n = cur[i].n;
    f.k = P.s[i].k; f.hc = P.s[i].hc; f.wc = P.s[i].wc;
    f.cand_base = P.s[i].cand_base; f.nk_off = P.s[i].nk_off; f.scf = P.s[i].scf;
  }
  k_final_gather<<<ns, 256, 0, stream>>>(keys, redA, redB, reg4, cb9, cinds,
                                         cx1, cy1, cx2, cy2, car, csc, fa);

  // per-scale NMS: mask (transposed) -> register-pipelined scan
  SMArgs ma{}; ma.ns = ns; ma.blk[0] = 0;
  SSArgs sa{};
  for (int i = 0; i < ns; ++i) {
    ma.base[i] = P.s[i].cand_base; ma.kk[i] = P.s[i].k;
    ma.blk[i+1] = ma.blk[i] + ((P.s[i].k + 31)/32) * 4;
    sa.base[i] = P.s[i].cand_base; sa.kk[i] = P.s[i].k;
  }
  k_smask<<<ma.blk[ns], 256, 0, stream>>>(cx1, cy1, cx2, cy2, car, smask, ma);
  k_sscan<<<ns, 64, 0, stream>>>(smask, csc, candk, sa);

  // global top-2048
  {
    int nb1 = (tot_k + 4095)/4096;
    RedArgs ra{}; ra.ne = 1; ra.outk = KG;
    ra.e[0].in_buf = 3; ra.e[0].in_off = 0; ra.e[0].n = tot_k;
    ra.e[0].blk_start = 0; ra.e[0].nblk = nb1; ra.e[0].out_off = 0;
    k_topk_reduce<<<nb1, 256, 0, stream>>>(keys, redA, redB, candk, redA, ra);
    int n2 = nb1*KG;
    int nb2 = (n2 + 4095)/4096;
    RedArgs rb{}; rb.ne = 1; rb.outk = KG;
    rb.e[0].in_buf = 1; rb.e[0].in_off = 0; rb.e[0].n = n2;
    rb.e[0].blk_start = 0; rb.e[0].nblk = nb2; rb.e[0].out_off = 0;
    k_topk_reduce<<<nb2, 256, 0, stream>>>(keys, redA, redB, candk, redB, rb);
  }
  k_gfinal<<<1, 256, 0, stream>>>(redB, cb9, cinds, gsort, gx1, gy1, gx2, gy2, gar, gsc);

  // global NMS: transposed mask -> register-pipelined scan
  k_gmask<<<512, 256, 0, stream>>>(gx1, gy1, gx2, gy2, gar, gmaskb);
  k_gscan<<<1, 64, 0, stream>>>(gmaskb, gsc, gkeep);

  k_finalize<<<(KG + 255)/256, 256, 0, stream>>>(gsort, gkeep, cb9, cinds, out);
}